// Round 1
// 116.808 us; speedup vs baseline: 1.0968x; 1.0968x over previous
//
#include <hip/hip_runtime.h>
#include <float.h>

// Problem constants (fixed by the reference): B=2, N=M=8192, G=256
#define B_ 2
#define N_ 8192
#define G_ 256
// CELL = abs(2*(-35)/256) = 70/256 = 0.2734375 exactly representable in fp32
constexpr float X_MIN_F = -35.0f;
constexpr float CELL_F  = 0.2734375f;

using u64 = unsigned long long;

// Workspace layout (bytes):
//   grid    i32[B*G*G]    [0, 524288)      packed (n<<1)|label, -1 invalid
//   accum   16B           [524288, 524304) {f32 sum, i32 cnt, u32 ticket, pad}
//   px      u64[CC][B*N]  [524352, ...)    per-chunk packed (distbits<<32)|idx
//   colpart f32[8][B*N]   after px         per-row-stripe column min (cham_y)
#define OFF_ACCUM 524288
#define OFF_PX    524352

// ---------------------------------------------------------------------------
// Fused symmetric 1-NN (L1). |a-b| is bitwise symmetric and both reference
// knn calls sum coords in the same order, so dir0/dir1 share one distance
// matrix D. One pass computes D once and reduces BOTH ways:
//   rows  (cham_x + argmin): thread-local, group-argmin scheme (min-tree over
//         8-col groups, strict < keeps earliest group, descending equality
//         rescan keeps smallest k, packed-u64 min across chunks).
//   cols  (cham_y, dist only): per-thread 4-row premin -> permlane32_swap
//         lane-pair min (VALU) -> 32x8 LDS transpose (padded, <=2-way banks)
//         -> 3-stage shfl_xor cluster reduce -> per-wave colW -> block min ->
//         global colpart[row_stripe][B*N], merged in reduce kernel (8 loads).
// Column data for the main loop is wave-uniform -> read from global with
// uniform addresses (SMEM path, no LDS pipe). LDS q copy kept only for the
// divergent rescan. Min chains written as fminf(fminf(a,b),c) for v_min3.
// Grid=-1 init and accum zeroing folded in (consumed after kernel boundary).
//   grid: (8 row-stripes, CC col-chunks, B)
// ---------------------------------------------------------------------------
template<int CC>
__global__ __launch_bounds__(256) void nn_kernel(const float* __restrict__ p_i,
                                                 const float* __restrict__ p_j,
                                                 u64* __restrict__ px,
                                                 float* __restrict__ colpart,
                                                 int* __restrict__ grid,
                                                 unsigned* __restrict__ accum)
{
    constexpr int COLS = N_ / CC;
    constexpr int NB   = 16 * CC;                // total blocks
    const int b    = blockIdx.z;
    const int tid  = threadIdx.x;
    const int lane = tid & 63;
    const int w    = tid >> 6;
    const int row0 = blockIdx.x * 1024 + tid * 4;
    const int c0   = blockIdx.y * COLS;

    __shared__ __align__(16) float q[COLS * 3];  // rescan copy only
    __shared__ float sc[4][8][35];               // per-wave merge scratch
    __shared__ float colW[4][COLS];              // per-wave column mins

    const float* __restrict__ Qg = p_j + ((size_t)b * N_ + c0) * 3;

    for (int t = tid; t < COLS * 3 / 4; t += 256)
        ((float4*)q)[t] = ((const float4*)Qg)[t];

    // folded init: grid = -1 (512 KB spread over all blocks), accum = 0
    {
        const int lin = blockIdx.x + 8 * (blockIdx.y + CC * blockIdx.z);
        constexpr int PER = 32768 / NB;          // uint4 per block
        if (tid < PER)
            ((uint4*)grid)[lin * PER + tid] = make_uint4(~0u, ~0u, ~0u, ~0u);
        if (lin == 0 && tid < 4) accum[tid] = 0u;
    }

    // 4 consecutive rows = 12 consecutive floats = 3 float4
    const float4* pp = (const float4*)(p_i + ((size_t)b * N_ + row0) * 3);
    float4 r0 = pp[0], r1 = pp[1], r2 = pp[2];
    float px_[4] = {r0.x, r0.w, r1.z, r2.y};
    float py_[4] = {r0.y, r1.x, r1.w, r2.z};
    float pz_[4] = {r0.z, r1.y, r2.x, r2.w};

    float best[4] = {FLT_MAX, FLT_MAX, FLT_MAX, FLT_MAX};
    int   gcol[4] = {0, 0, 0, 0};

    for (int jg = 0; jg < COLS; jg += 8) {
        // wave-uniform column loads (scalarized to s_load; bit-same as q[])
        const float4* qv = (const float4*)(Qg + (size_t)jg * 3);
        float4 v0 = qv[0], v1 = qv[1], v2 = qv[2];
        float4 v3 = qv[3], v4 = qv[4], v5 = qv[5];
        float qx[8] = {v0.x, v0.w, v1.z, v2.y, v3.x, v3.w, v4.z, v5.y};
        float qy[8] = {v0.y, v1.x, v1.w, v2.z, v3.y, v4.x, v4.w, v5.z};
        float qz[8] = {v0.z, v1.y, v2.x, v2.w, v3.z, v4.y, v5.x, v5.w};

        float dm[4][8];
#pragma unroll
        for (int r = 0; r < 4; r++) {
#pragma unroll
            for (int k = 0; k < 8; k++)
                // bit-match reference: (|d0| + |d1|) + |d2|, left-assoc
                dm[r][k] = (fabsf(px_[r] - qx[k]) + fabsf(py_[r] - qy[k]))
                           + fabsf(pz_[r] - qz[k]);
            // row min: chain form -> v_min3 fusion (min is assoc/comm, no NaN)
            float m = fminf(fminf(dm[r][0], dm[r][1]), dm[r][2]);
            m = fminf(fminf(m, dm[r][3]), dm[r][4]);
            m = fminf(fminf(m, dm[r][5]), dm[r][6]);
            m = fminf(m, dm[r][7]);
            bool lt = m < best[r];               // strict < -> earliest group
            best[r] = lt ? m : best[r];
            gcol[r] = lt ? jg : gcol[r];
        }

        // column partial: min over this thread's 4 rows (min3 + min)
        float part[8];
#pragma unroll
        for (int k = 0; k < 8; k++)
            part[k] = fminf(fminf(fminf(dm[0][k], dm[1][k]), dm[2][k]),
                            dm[3][k]);

        // lane L <-> L+32 pair-min, pure VALU (both outputs of the swap used)
#pragma unroll
        for (int k = 0; k < 8; k++) {
            unsigned a = __float_as_uint(part[k]);
            auto pr = __builtin_amdgcn_permlane32_swap(a, a, false, false);
            part[k] = fminf(__uint_as_float(pr[0]), __uint_as_float(pr[1]));
        }
        // 32x8 transpose through padded LDS (writes: 32 distinct banks;
        // dup lanes L/L+32 write same addr+value). Reads: <=2-way aliasing.
#pragma unroll
        for (int k = 0; k < 8; k++)
            sc[w][k][lane & 31] = part[k];
        const int kc = lane >> 3, mc = lane & 7;
        float c4 = fminf(fminf(sc[w][kc][4 * mc],     sc[w][kc][4 * mc + 1]),
                         fminf(sc[w][kc][4 * mc + 2], sc[w][kc][4 * mc + 3]));
        c4 = fminf(c4, __shfl_xor(c4, 1));
        c4 = fminf(c4, __shfl_xor(c4, 2));
        c4 = fminf(c4, __shfl_xor(c4, 4));
        if (mc == 0) colW[w][jg + kc] = c4;      // final for this wave's rows
    }

    __syncthreads();                             // colW + q copy complete

    // block-level column min -> global partial per (row-stripe, column)
    for (int t = tid; t < COLS; t += 256) {
        float c = fminf(fminf(colW[0][t], colW[1][t]),
                        fminf(colW[2][t], colW[3][t]));
        colpart[(size_t)blockIdx.x * (B_ * N_) + (size_t)b * N_ + c0 + t] = c;
    }

    // rescan winning group: recompute identical expressions, descending
    // equality overwrite -> smallest k = first occurrence.
    int bidx[4];
#pragma unroll
    for (int r = 0; r < 4; r++) {
        const float4* qv = (const float4*)&q[gcol[r] * 3];
        float4 v0 = qv[0], v1 = qv[1], v2 = qv[2];
        float4 v3 = qv[3], v4 = qv[4], v5 = qv[5];
        float qx[8] = {v0.x, v0.w, v1.z, v2.y, v3.x, v3.w, v4.z, v5.y};
        float qy[8] = {v0.y, v1.x, v1.w, v2.z, v3.y, v4.x, v4.w, v5.z};
        float qz[8] = {v0.z, v1.y, v2.x, v2.w, v3.z, v4.y, v5.x, v5.w};
        int kk = 0;
#pragma unroll
        for (int k = 7; k >= 0; k--) {
            float d = (fabsf(px_[r] - qx[k]) + fabsf(py_[r] - qy[k]))
                      + fabsf(pz_[r] - qz[k]);
            kk = (d == best[r]) ? k : kk;
        }
        bidx[r] = c0 + gcol[r] + kk;
    }
    const size_t o = (size_t)blockIdx.y * (B_ * N_) + b * N_ + row0;
#pragma unroll
    for (int r = 0; r < 4; r++)
        // non-negative fp32 bits order like unsigned; idx in low bits ->
        // u64 min over chunks keeps (min dist, then min idx) = first occ.
        px[o + r] = ((u64)__float_as_uint(best[r]) << 32) | (unsigned)bidx[r];
}

// ---------------------------------------------------------------------------
// Cross-chunk reduce + label + scatter. 256 blocks x 256 threads: 4 threads
// per point (LDS atomicMin combine), 64 points per block. Row side: u64 min
// over CC chunks; column side: fminf over the 8 row-stripe partials (2 per
// thread-group). Last-write-wins in point order n == max n wins -> atomicMax
// on packed (n<<1 | label); grid initialized to -1 by nn_kernel.
// ---------------------------------------------------------------------------
template<int CC>
__global__ __launch_bounds__(256) void reduce_scatter_kernel(
    const u64* __restrict__ px, const float* __restrict__ cp,
    const float* __restrict__ flow, const int* __restrict__ nflow,
    const float* __restrict__ Pj, int* __restrict__ grid)
{
    __shared__ u64      sbx[64];
    __shared__ unsigned sby[64];
    const int tid = threadIdx.x;
    const int p   = tid & 63;                    // point within block
    const int g   = tid >> 6;                    // group 0..3
    constexpr int CPG = CC / 4;                  // px chunks per group

    if (tid < 64) { sbx[tid] = ~0ull; sby[tid] = ~0u; }
    __syncthreads();

    const int pt = blockIdx.x * 64 + p;          // in [0, B*N)
    u64 bx = ~0ull;
#pragma unroll
    for (int k = 0; k < CPG; k++) {
        int c = g * CPG + k;
        u64 v = px[(size_t)c * (B_ * N_) + pt];
        bx = v < bx ? v : bx;
    }
    float by = fminf(cp[(size_t)(2 * g)     * (B_ * N_) + pt],
                     cp[(size_t)(2 * g + 1) * (B_ * N_) + pt]);
    atomicMin(&sbx[p], bx);
    atomicMin(&sby[p], __float_as_uint(by));
    __syncthreads();

    if (tid < 64) {
        u64 fx = sbx[tid];
        float dx = __uint_as_float((unsigned)(fx >> 32));
        float dy = __uint_as_float(sby[tid]);
        float rigid = (dx + dy) * 0.5f;

        const int i = blockIdx.x * 64 + tid;
        const int b = i >> 13;                   // N = 8192
        const int n = i & (N_ - 1);

        bool dyn  = flow[i] > rigid;
        int label = dyn ? 1 : 0;
        int idx   = dyn ? nflow[i] : (int)(unsigned)(fx & 0xFFFFFFFFull);

        const float* qp = Pj + ((size_t)b * N_ + idx) * 3;
        float xx = qp[0], yy = qp[1];

        // bit-match ref: (p - shift) / CELL, IEEE fp32 divide, trunc cast
        int cx = (int)((xx - X_MIN_F) / CELL_F);
        int cy = (int)((yy - X_MIN_F) / CELL_F);

        atomicMax(&grid[(b << 16) + cx * G_ + cy], (n << 1) | label);
    }
}

// ---------------------------------------------------------------------------
// Cross-entropy over valid grid cells + fused finalize: last block (ticket)
// reads the device-scope accumulators and writes the loss.
// ---------------------------------------------------------------------------
__global__ __launch_bounds__(256) void ce_kernel(const float* __restrict__ mos,
                                                 const int* __restrict__ grid,
                                                 float* __restrict__ accum,
                                                 float* __restrict__ out)
{
    int i = blockIdx.x * 256 + threadIdx.x;      // i in [0, B*G*G) = 131072
    float lsum = 0.0f;
    int   lcnt = 0;

    int packed = grid[i];
    if (packed >= 0) {
        int b    = i >> 16;                      // G*G = 65536
        int cell = i & 0xFFFF;
        float m0 = mos[((size_t)b * 2 + 0) * 65536 + cell];
        float m1 = mos[((size_t)b * 2 + 1) * 65536 + cell];
        float mx = fmaxf(m0, m1);
        float lse = logf(expf(m0 - mx) + expf(m1 - mx));
        float sh  = ((packed & 1) ? m1 : m0) - mx;   // stable log_softmax
        lsum = sh - lse;
        lcnt = 1;
    }

    // wave-64 shuffle reduction
#pragma unroll
    for (int o = 32; o > 0; o >>= 1) {
        lsum += __shfl_down(lsum, o);
        lcnt += __shfl_down(lcnt, o);
    }
    __shared__ float wsum[4];
    __shared__ int   wcnt[4];
    int wave = threadIdx.x >> 6;
    if ((threadIdx.x & 63) == 0) { wsum[wave] = lsum; wcnt[wave] = lcnt; }
    __syncthreads();
    if (threadIdx.x == 0) {
        float s = wsum[0] + wsum[1] + wsum[2] + wsum[3];
        int   c = wcnt[0] + wcnt[1] + wcnt[2] + wcnt[3];
        atomicAdd(&accum[0], s);
        atomicAdd((int*)&accum[1], c);
        __threadfence();
        unsigned t = atomicAdd((unsigned*)&accum[2], 1u);
        if (t == gridDim.x - 1) {
            float S = atomicAdd(&accum[0], 0.0f);
            int   C = atomicAdd((int*)&accum[1], 0);
            out[0] = -S / (float)(C > 0 ? C : 1);
        }
    }
}

// ---------------------------------------------------------------------------
template<int CC>
static void run(const float* p_i, const float* mos, const float* p_j,
                const float* flow, const int* nflow, float* out,
                char* ws, hipStream_t stream)
{
    int*   grid    = (int*)ws;
    float* accum   = (float*)(ws + OFF_ACCUM);
    u64*   px      = (u64*)(ws + OFF_PX);
    float* colpart = (float*)(ws + OFF_PX + (size_t)CC * B_ * N_ * 8);

    dim3 g(8, CC, 2);
    nn_kernel<CC><<<g, 256, 0, stream>>>(p_i, p_j, px, colpart, (int*)grid,
                                         (unsigned*)accum);
    reduce_scatter_kernel<CC><<<256, 256, 0, stream>>>(px, colpart, flow,
                                                       nflow, p_j, grid);
    ce_kernel<<<(B_ * G_ * G_) / 256, 256, 0, stream>>>(mos, grid, accum, out);
}

extern "C" void kernel_launch(void* const* d_in, const int* in_sizes, int n_in,
                              void* d_out, int out_size, void* d_ws, size_t ws_size,
                              hipStream_t stream)
{
    const float* p_i   = (const float*)d_in[0];   // (B,N,3)
    const float* mos   = (const float*)d_in[1];   // (B,2,G,G)
    const float* p_j   = (const float*)d_in[2];   // (B,M,3)
    const float* flow  = (const float*)d_in[3];   // (B,N)
    const int*   nflow = (const int*)d_in[4];     // (B,N,1)
    float* out = (float*)d_out;
    char* ws = (char*)d_ws;

    // scratch: OFF_PX + CC*B*N*8 + 8*B*N*4 bytes.
    // CC=64 -> ~9.4 MB, 32 -> ~5.2 MB, 8 -> ~2.1 MB
    constexpr size_t CPART = (size_t)8 * B_ * N_ * 4;
    if (ws_size >= OFF_PX + (size_t)64 * B_ * N_ * 8 + CPART)
        run<64>(p_i, mos, p_j, flow, nflow, out, ws, stream);
    else if (ws_size >= OFF_PX + (size_t)32 * B_ * N_ * 8 + CPART)
        run<32>(p_i, mos, p_j, flow, nflow, out, ws, stream);
    else
        run<8>(p_i, mos, p_j, flow, nflow, out, ws, stream);
}